// Round 4
// baseline (801.708 us; speedup 1.0000x reference)
//
#include <hip/hip_runtime.h>

typedef unsigned short u16;
typedef unsigned int u32;
typedef __attribute__((ext_vector_type(8))) short bf16x8;
typedef __attribute__((ext_vector_type(4))) float f32x4;

__device__ __forceinline__ u16 f2bf(float f) {
  u32 u = __builtin_bit_cast(u32, f);
  u = u + 0x7FFFu + ((u >> 16) & 1u);
  return (u16)(u >> 16);
}
__device__ __forceinline__ float bf2f(u16 s) {
  return __builtin_bit_cast(float, (u32)s << 16);
}

__device__ __forceinline__ void gload_lds16(const u16* g, u16* l) {
  __builtin_amdgcn_global_load_lds(
      (const __attribute__((address_space(1))) u32*)g,
      (__attribute__((address_space(3))) u32*)l, 16, 0, 0);
}

// ---------------------------------------------------------------------------
// zero the stats accumulator (2048 floats)
// ---------------------------------------------------------------------------
__global__ __launch_bounds__(512) void k_zero(float* __restrict__ p) {
  float4 z = {0.f, 0.f, 0.f, 0.f};
  *(float4*)(p + threadIdx.x * 4) = z;
}

// ---------------------------------------------------------------------------
// fp32 -> bf16 conversion for all four 512x1024 weight matrices in one launch
// ---------------------------------------------------------------------------
__global__ __launch_bounds__(256) void k_cvt4(
    const float* __restrict__ s0, const float* __restrict__ s1,
    const float* __restrict__ s2, const float* __restrict__ s3,
    u16* __restrict__ d0, u16* __restrict__ d1, u16* __restrict__ d2,
    u16* __restrict__ d3) {
  int gid = blockIdx.x * 256 + threadIdx.x;
  int which = gid >> 17;                // 131072 threads per matrix
  int loc = (gid & 131071) * 4;
  const float* s = which == 0 ? s0 : which == 1 ? s1 : which == 2 ? s2 : s3;
  u16* d = which == 0 ? d0 : which == 1 ? d1 : which == 2 ? d2 : d3;
  float4 v = *(const float4*)(s + loc);
  u32 lo = (u32)f2bf(v.x) | ((u32)f2bf(v.y) << 16);
  u32 hi = (u32)f2bf(v.z) | ((u32)f2bf(v.w) << 16);
  uint2 o; o.x = lo; o.y = hi;
  *(uint2*)(d + loc) = o;
}

// ---------------------------------------------------------------------------
// Fused: x [B,1024,64,64] fp32 -> xT [B,4096,1024] bf16 (transpose+cast)
//                              -> xpT [B,1024,1024] bf16 (2x2 maxpool + T)
// ---------------------------------------------------------------------------
__global__ __launch_bounds__(256) void k_transpose_pool(
    const float* __restrict__ x, u16* __restrict__ xT, u16* __restrict__ xpT) {
  __shared__ u16 lds[128 * 64];
  const int t = threadIdx.x;
  const int c0 = blockIdx.x * 64;
  const int by = blockIdx.y;        // h0 = by*2
  const int b = blockIdx.z;

  {
    const int nf = (t & 31) * 4;
    const int swz = 8 * (t & 7);
    const float* xb =
        x + ((size_t)(b * 1024 + c0 + (t >> 5)) * 4096) + by * 128 + nf;
#pragma unroll
    for (int u = 0; u < 8; ++u) {
      const int c_l = (t >> 5) + 8 * u;
      float4 v = *(const float4*)(xb + (size_t)(8 * u) * 4096);
      const int col = c_l ^ swz;
      lds[(nf + 0) * 64 + col] = f2bf(v.x);
      lds[(nf + 1) * 64 + col] = f2bf(v.y);
      lds[(nf + 2) * 64 + col] = f2bf(v.z);
      lds[(nf + 3) * 64 + col] = f2bf(v.w);
    }
  }
  __syncthreads();
  {
#pragma unroll
    for (int v = 0; v < 4; ++v) {
      const int idx = t + 256 * v;
      const int n_l = idx >> 3;
      const int cb = (idx & 7) * 8;
      const int col = cb ^ (8 * ((n_l >> 2) & 7));
      bf16x8 d = *(const bf16x8*)&lds[n_l * 64 + col];
      *(bf16x8*)&xT[((size_t)b * 4096 + by * 128 + n_l) * 1024 + c0 + cb] = d;
    }
  }
  {
    const int m_w = t >> 3;
    const int cb = (t & 7) * 8;
    const int na = 2 * m_w, nb = na + 1, nc = na + 64, nd = na + 65;
    bf16x8 va = *(const bf16x8*)&lds[na * 64 + (cb ^ (8 * ((na >> 2) & 7)))];
    bf16x8 vb = *(const bf16x8*)&lds[nb * 64 + (cb ^ (8 * ((nb >> 2) & 7)))];
    bf16x8 vc = *(const bf16x8*)&lds[nc * 64 + (cb ^ (8 * ((nc >> 2) & 7)))];
    bf16x8 vd = *(const bf16x8*)&lds[nd * 64 + (cb ^ (8 * ((nd >> 2) & 7)))];
    bf16x8 o;
#pragma unroll
    for (int j = 0; j < 8; ++j) {
      float m = fmaxf(fmaxf(bf2f((u16)va[j]), bf2f((u16)vb[j])),
                      fmaxf(bf2f((u16)vc[j]), bf2f((u16)vd[j])));
      o[j] = (short)f2bf(m);
    }
    *(bf16x8*)&xpT[((size_t)b * 1024 + by * 32 + m_w) * 1024 + c0 + cb] = o;
  }
}

// ---------------------------------------------------------------------------
// 128x128 NT GEMM (round-2 winner): for small-grid GEMMs (phi, g).
// Double-buffered LDS, prefetch-before-compute, one barrier per K-step.
// ---------------------------------------------------------------------------
template <int BIAS_MODE>  // 0 none, 1 row (bias[i]), 2 col (bias[j])
__global__ __launch_bounds__(256, 2) void gemm_nt(
    const u16* __restrict__ A, long aBS, const u16* __restrict__ Bm, long bBS,
    u16* __restrict__ Cm, long cBS, const float* __restrict__ bias, int N,
    int K, float scale) {
  __shared__ u16 Alds[2][128 * 32];
  __shared__ u16 Blds[2][128 * 32];
  const int t = threadIdx.x;
  const int b = blockIdx.z;
  const int bm = blockIdx.y, bn = blockIdx.x;
  const u16* Ab = A + (size_t)b * aBS + (size_t)bm * 128 * K;
  const u16* Bb = Bm + (size_t)b * bBS + (size_t)bn * 128 * K;

  const int lane = t & 63;
  const int w = t >> 6;
  const int wrow = w >> 1, wcol = w & 1;
  const int lr = lane & 15;
  const int kg = lane >> 4;

  f32x4 acc[4][4] = {};

  const int e0 = t * 8;
  const int r0 = e0 >> 5;
  const int k0i = e0 & 31;
  const int steps = K >> 5;

#define STAGE(buf, ks)                                                   \
  do {                                                                   \
    const int kb = (ks) * 32;                                            \
    gload_lds16(Ab + (size_t)r0 * K + kb + k0i, &Alds[buf][e0]);         \
    gload_lds16(Ab + (size_t)(r0 + 64) * K + kb + k0i,                   \
                &Alds[buf][e0 + 2048]);                                  \
    gload_lds16(Bb + (size_t)r0 * K + kb + k0i, &Blds[buf][e0]);         \
    gload_lds16(Bb + (size_t)(r0 + 64) * K + kb + k0i,                   \
                &Blds[buf][e0 + 2048]);                                  \
  } while (0)

  STAGE(0, 0);
  for (int ks = 0; ks < steps; ++ks) {
    const int cur = ks & 1;
    __syncthreads();
    if (ks + 1 < steps) STAGE(cur ^ 1, ks + 1);
    bf16x8 af[4], bfr[4];
#pragma unroll
    for (int i = 0; i < 4; ++i) {
      af[i] =
          *(const bf16x8*)&Alds[cur][(wrow * 64 + i * 16 + lr) * 32 + kg * 8];
      bfr[i] =
          *(const bf16x8*)&Blds[cur][(wcol * 64 + i * 16 + lr) * 32 + kg * 8];
    }
#pragma unroll
    for (int i = 0; i < 4; ++i)
#pragma unroll
      for (int j = 0; j < 4; ++j)
        acc[i][j] = __builtin_amdgcn_mfma_f32_16x16x32_bf16(af[i], bfr[j],
                                                            acc[i][j], 0, 0, 0);
  }
#undef STAGE

  u16* Cb = Cm + (size_t)b * cBS;
#pragma unroll
  for (int i = 0; i < 4; ++i) {
#pragma unroll
    for (int j = 0; j < 4; ++j) {
      int row0 = bm * 128 + wrow * 64 + i * 16 + kg * 4;
      int col = bn * 128 + wcol * 64 + j * 16 + lr;
      float bj = (BIAS_MODE == 2) ? bias[col] : 0.f;
#pragma unroll
      for (int r = 0; r < 4; ++r) {
        float v = acc[i][j][r] * scale;
        if (BIAS_MODE == 1) v += bias[row0 + r];
        if (BIAS_MODE == 2) v += bj;
        Cb[(size_t)(row0 + r) * N + col] = f2bf(v);
      }
    }
  }
}

// ---------------------------------------------------------------------------
// 256x256 8-phase NT GEMM (big-grid GEMMs). STATS=1 additionally accumulates
// per-output-row sum/sumsq (post scale+bias) into statsp[2*row(+1)] atomics.
// ---------------------------------------------------------------------------
template <int BIAS_MODE, int STATS>
__global__ __launch_bounds__(512) void gemm256(
    const u16* __restrict__ A, long aBS, const u16* __restrict__ Bm, long bBS,
    u16* __restrict__ Cm, long cBS, const float* __restrict__ bias, int N,
    int K, float scale, float* __restrict__ statsp) {
  __shared__ u16 ALDS[2][16384];
  __shared__ u16 BLDS[2][16384];
  const int t = threadIdx.x;
  u32 gx = gridDim.x, gy = gridDim.y;
  u32 nwg = gx * gy * gridDim.z;
  u32 wg = blockIdx.x + gx * (blockIdx.y + gy * blockIdx.z);
  u32 swz = (wg & 7) * (nwg >> 3) + (wg >> 3);
  const int bn = swz % gx;
  u32 tmp = swz / gx;
  const int bm = tmp % gy;
  const int b = tmp / gy;

  const u16* Agb = A + (size_t)b * aBS + (size_t)bm * 256 * K;
  const u16* Bgb = Bm + (size_t)b * bBS + (size_t)bn * 256 * K;

  const int lane = t & 63;
  const int wid = t >> 6;
  const int wr = wid >> 2;
  const int wc = wid & 3;
  const int lr = lane & 15;
  const int kg = (lane >> 4) & 3;
  const int T = K >> 6;

  f32x4 acc[8][4] = {};

#define STAGE_G(LDSARR, GB, h, ktn)                                          \
  if ((ktn) < T) {                                                           \
    {                                                                        \
      const int r = t >> 3;                                                  \
      gload_lds16(GB + (size_t)((h)*128 + r) * K + (size_t)(ktn)*64 +        \
                      (((t & 7) ^ (r & 7)) * 8),                             \
                  &LDSARR[(ktn) & 1][(h)*8192 + t * 8]);                     \
    }                                                                        \
    {                                                                        \
      const int idx = 512 + t;                                               \
      const int r = idx >> 3;                                                \
      gload_lds16(GB + (size_t)((h)*128 + r) * K + (size_t)(ktn)*64 +        \
                      (((t & 7) ^ (r & 7)) * 8),                             \
                  &LDSARR[(ktn) & 1][(h)*8192 + idx * 8]);                   \
    }                                                                        \
  }
#define STAGE_A(h, ktn) STAGE_G(ALDS, Agb, h, ktn)
#define STAGE_B(h, ktn) STAGE_G(BLDS, Bgb, h, ktn)

#define LDA4(mh, kk)                                                         \
  _Pragma("unroll") for (int m2 = 0; m2 < 4; ++m2) {                         \
    const int row = wr * 128 + ((mh)*4 + m2) * 16 + lr;                      \
    aF[m2] = *(const bf16x8*)&ALDS[cb][row * 64 +                            \
                                       ((((kk)*4 + kg) ^ (lr & 7)) * 8)];    \
  }
#define LDB4(kk)                                                             \
  _Pragma("unroll") for (int n = 0; n < 4; ++n) {                            \
    const int row = wc * 64 + n * 16 + lr;                                   \
    bF[n] = *(const bf16x8*)&BLDS[cb][row * 64 +                             \
                                      ((((kk)*4 + kg) ^ (lr & 7)) * 8)];     \
  }
#define MFMA16(M0)                                                           \
  __builtin_amdgcn_s_setprio(1);                                             \
  _Pragma("unroll") for (int n = 0; n < 4; ++n) {                            \
    acc[(M0) + 0][n] = __builtin_amdgcn_mfma_f32_16x16x32_bf16(              \
        aF[0], bF[n], acc[(M0) + 0][n], 0, 0, 0);                            \
    acc[(M0) + 1][n] = __builtin_amdgcn_mfma_f32_16x16x32_bf16(              \
        aF[1], bF[n], acc[(M0) + 1][n], 0, 0, 0);                            \
    acc[(M0) + 2][n] = __builtin_amdgcn_mfma_f32_16x16x32_bf16(              \
        aF[2], bF[n], acc[(M0) + 2][n], 0, 0, 0);                            \
    acc[(M0) + 3][n] = __builtin_amdgcn_mfma_f32_16x16x32_bf16(              \
        aF[3], bF[n], acc[(M0) + 3][n], 0, 0, 0);                            \
  }                                                                          \
  __builtin_amdgcn_s_setprio(0);
#define CFENCE asm volatile("" ::: "memory")

  STAGE_B(0, 0);
  STAGE_B(1, 0);
  STAGE_A(0, 0);
  STAGE_A(1, 0);
  STAGE_B(0, 1);

  for (int kt = 0; kt < T; ++kt) {
    const int cb = kt & 1;
    bf16x8 aF[4], bF[4];
    asm volatile("s_waitcnt vmcnt(2)" ::: "memory");
    __builtin_amdgcn_s_barrier();
    STAGE_B(1, kt + 1);
    LDB4(0);
    LDA4(0, 0);
    MFMA16(0);
    CFENCE;
    __builtin_amdgcn_s_barrier();
    STAGE_A(0, kt + 1);
    LDA4(1, 0);
    MFMA16(4);
    CFENCE;
    __builtin_amdgcn_s_barrier();
    STAGE_A(1, kt + 1);
    LDB4(1);
    LDA4(0, 1);
    MFMA16(0);
    CFENCE;
    __builtin_amdgcn_s_barrier();
    STAGE_B(0, kt + 2);
    LDA4(1, 1);
    MFMA16(4);
    CFENCE;
    __builtin_amdgcn_s_barrier();
  }

  u16* Cb = Cm + (size_t)b * cBS;
  if constexpr (!STATS) {
#pragma unroll
    for (int m = 0; m < 8; ++m) {
      const int row0 = bm * 256 + wr * 128 + m * 16 + kg * 4;
#pragma unroll
      for (int n = 0; n < 4; ++n) {
        const int col = bn * 256 + wc * 64 + n * 16 + lr;
        float bj = (BIAS_MODE == 2) ? bias[col] : 0.f;
#pragma unroll
        for (int r = 0; r < 4; ++r) {
          float v = acc[m][n][r] * scale;
          if (BIAS_MODE == 1) v += bias[row0 + r];
          if (BIAS_MODE == 2) v += bj;
          Cb[(size_t)(row0 + r) * N + col] = f2bf(v);
        }
      }
    }
  } else {
#pragma unroll
    for (int m = 0; m < 8; ++m) {
      const int row0 = bm * 256 + wr * 128 + m * 16 + kg * 4;
#pragma unroll
      for (int r = 0; r < 4; ++r) {
        const int row = row0 + r;
        float bi = (BIAS_MODE == 1) ? bias[row] : 0.f;
        float s = 0.f, q = 0.f;
#pragma unroll
        for (int n = 0; n < 4; ++n) {
          const int col = bn * 256 + wc * 64 + n * 16 + lr;
          float v = acc[m][n][r] * scale + bi;
          if (BIAS_MODE == 2) v += bias[col];
          Cb[(size_t)row * N + col] = f2bf(v);
          s += v;
          q += v * v;
        }
#pragma unroll
        for (int off = 1; off < 16; off <<= 1) {
          s += __shfl_xor(s, off);
          q += __shfl_xor(q, off);
        }
        if (lr == 0) {
          atomicAdd(&statsp[2 * row], s);
          atomicAdd(&statsp[2 * row + 1], q);
        }
      }
    }
  }
#undef STAGE_G
#undef STAGE_A
#undef STAGE_B
#undef LDA4
#undef LDB4
#undef MFMA16
#undef CFENCE
}

// ---------------------------------------------------------------------------
// Row softmax, in place. Rows of 1024 bf16, one wave per row, 4 rows/block.
// ---------------------------------------------------------------------------
__global__ __launch_bounds__(256) void k_softmax(u16* __restrict__ S) {
  const int t = threadIdx.x;
  const int lane = t & 63;
  const size_t row = (size_t)blockIdx.x * 4 + (t >> 6);
  u16* p = S + row * 1024 + lane * 16;
  uint4 d0 = *(const uint4*)p;
  uint4 d1 = *(const uint4*)(p + 8);
  u32 u[8] = {d0.x, d0.y, d0.z, d0.w, d1.x, d1.y, d1.z, d1.w};
  float v[16];
#pragma unroll
  for (int i = 0; i < 8; ++i) {
    v[2 * i] = bf2f((u16)(u[i] & 0xffff));
    v[2 * i + 1] = bf2f((u16)(u[i] >> 16));
  }
  float m = v[0];
#pragma unroll
  for (int i = 1; i < 16; ++i) m = fmaxf(m, v[i]);
  for (int o = 32; o > 0; o >>= 1) m = fmaxf(m, __shfl_xor(m, o));
  const float LOG2E = 1.44269504088896f;
  float s = 0.f;
#pragma unroll
  for (int i = 0; i < 16; ++i) {
    v[i] = exp2f((v[i] - m) * LOG2E);
    s += v[i];
  }
  for (int o = 32; o > 0; o >>= 1) s += __shfl_xor(s, o);
  float inv = 1.0f / s;
#pragma unroll
  for (int i = 0; i < 8; ++i)
    u[i] = (u32)f2bf(v[2 * i] * inv) | ((u32)f2bf(v[2 * i + 1] * inv) << 16);
  uint4 o0; o0.x = u[0]; o0.y = u[1]; o0.z = u[2]; o0.w = u[3];
  uint4 o1; o1.x = u[4]; o1.y = u[5]; o1.z = u[6]; o1.w = u[7];
  *(uint4*)p = o0;
  *(uint4*)(p + 8) = o1;
}

// ---------------------------------------------------------------------------
// BN apply + residual: out = x + (z-mean)*rsqrt(var+eps)*gamma + beta
// ---------------------------------------------------------------------------
__global__ __launch_bounds__(256) void k_apply(
    const float* __restrict__ x, const u16* __restrict__ z,
    const float2* __restrict__ stats, const float* __restrict__ gamma,
    const float* __restrict__ beta, float* __restrict__ out) {
  size_t i4 = (size_t)blockIdx.x * 256 + threadIdx.x;
  size_t e = i4 * 4;
  int c = (int)((e >> 12) & 1023);
  float2 st = stats[c];
  const float cnt = 1.0f / 32768.0f;
  float mean = st.x * cnt;
  float var = st.y * cnt - mean * mean;
  float g = rsqrtf(var + 1e-5f) * gamma[c];
  float sh = beta[c] - mean * g;
  float4 xv = *(const float4*)(x + e);
  uint2 zd = *(const uint2*)(z + e);
  float z0 = bf2f((u16)(zd.x & 0xffff)), z1 = bf2f((u16)(zd.x >> 16));
  float z2 = bf2f((u16)(zd.y & 0xffff)), z3 = bf2f((u16)(zd.y >> 16));
  float4 ov;
  ov.x = xv.x + z0 * g + sh;
  ov.y = xv.y + z1 * g + sh;
  ov.z = xv.z + z2 * g + sh;
  ov.w = xv.w + z3 * g + sh;
  *(float4*)(out + e) = ov;
}

// ---------------------------------------------------------------------------
extern "C" void kernel_launch(void* const* d_in, const int* in_sizes, int n_in,
                              void* d_out, int out_size, void* d_ws,
                              size_t ws_size, hipStream_t stream) {
  const float* x = (const float*)d_in[0];
  const float* theta_w = (const float*)d_in[1];
  const float* theta_b = (const float*)d_in[2];
  const float* phi_w = (const float*)d_in[3];
  const float* phi_b = (const float*)d_in[4];
  const float* g_w = (const float*)d_in[5];
  const float* g_b = (const float*)d_in[6];
  const float* wz_w = (const float*)d_in[7];
  const float* wz_b = (const float*)d_in[8];
  const float* gamma = (const float*)d_in[9];
  const float* beta = (const float*)d_in[10];
  float* out = (float*)d_out;

  char* w = (char*)d_ws;
  const size_t MiB = (size_t)1 << 20;
  u16* WT = (u16*)(w + 0 * MiB);
  u16* WP = (u16*)(w + 1 * MiB);
  u16* WG = (u16*)(w + 2 * MiB);
  u16* WZ = (u16*)(w + 3 * MiB);
  u16* XT = (u16*)(w + 4 * MiB);      // [8][4096][1024] 64 MiB
  u16* XPT = (u16*)(w + 68 * MiB);    // [8][1024][1024] 16 MiB
  u16* THETA = (u16*)(w + 84 * MiB);  // [8][4096][512]  32 MiB
  u16* PHI = (u16*)(w + 116 * MiB);   // [8][1024][512]   8 MiB
  u16* G = (u16*)(w + 124 * MiB);     // [8][512][1024]   8 MiB
  u16* S = XT;                        // reuse xT region (dead after theta GEMM)
  u16* YT = (u16*)(w + 132 * MiB);    // [8][4096][512]  32 MiB
  u16* Z = S;                         // reuse again (P dead after yT GEMM)
  float* stats = (float*)(w + 164 * MiB);

  // zero BN-stats accumulator; weights -> bf16 (one launch)
  k_zero<<<1, 512, 0, stream>>>(stats);
  k_cvt4<<<2048, 256, 0, stream>>>(theta_w, phi_w, g_w, wz_w, WT, WP, WG, WZ);
  // x -> xT, xpT
  k_transpose_pool<<<dim3(16, 32, 8), 256, 0, stream>>>(x, XT, XPT);
  // thetaT[n,ci] = xT @ theta_w^T + theta_b  (batch folded into M=32768)
  gemm256<2, 0><<<dim3(2, 128, 1), 512, 0, stream>>>(
      XT, 0, WT, 0, THETA, 0, theta_b, 512, 1024, 1.0f, nullptr);
  // phiT[m,ci]  (128^2 tile: small-grid GEMM)
  gemm_nt<2><<<dim3(4, 8, 8), 256, 0, stream>>>(
      XPT, (long)1024 * 1024, WP, 0, PHI, (long)1024 * 512, phi_b, 512, 1024,
      1.0f);
  // g[ci,m]  (128^2 tile: small-grid GEMM)
  gemm_nt<1><<<dim3(8, 4, 8), 256, 0, stream>>>(
      WG, 0, XPT, (long)1024 * 1024, G, (long)512 * 1024, g_b, 1024, 1024,
      1.0f);
  // S[n,m] = thetaT . phiT^T * scale
  gemm256<0, 0><<<dim3(4, 16, 8), 512, 0, stream>>>(
      THETA, (long)4096 * 512, PHI, (long)1024 * 512, S, (long)4096 * 1024,
      nullptr, 1024, 512, 0.04419417382415922f, nullptr);
  // softmax rows (in place -> P)
  k_softmax<<<8192, 256, 0, stream>>>(S);
  // yT[n,ci] = P . g^T
  gemm256<0, 0><<<dim3(2, 16, 8), 512, 0, stream>>>(
      S, (long)4096 * 1024, G, (long)512 * 1024, YT, (long)4096 * 512, nullptr,
      512, 1024, 1.0f, nullptr);
  // z[o,n] = wz . yT^T + wz_b, with fused per-channel sum/sumsq atomics
  gemm256<1, 1><<<dim3(16, 4, 8), 512, 0, stream>>>(
      WZ, 0, YT, (long)4096 * 512, Z, (long)1024 * 4096, wz_b, 4096, 512, 1.0f,
      stats);
  // BN apply + residual
  k_apply<<<32768, 256, 0, stream>>>(x, Z, (const float2*)stats, gamma, beta,
                                     out);

  (void)in_sizes; (void)n_in; (void)out_size; (void)ws_size;
}

// Round 5
// 586.472 us; speedup vs baseline: 1.3670x; 1.3670x over previous
//
#include <hip/hip_runtime.h>

typedef unsigned short u16;
typedef unsigned int u32;
typedef __attribute__((ext_vector_type(8))) short bf16x8;
typedef __attribute__((ext_vector_type(4))) float f32x4;

__device__ __forceinline__ u16 f2bf(float f) {
  u32 u = __builtin_bit_cast(u32, f);
  u = u + 0x7FFFu + ((u >> 16) & 1u);
  return (u16)(u >> 16);
}
__device__ __forceinline__ float bf2f(u16 s) {
  return __builtin_bit_cast(float, (u32)s << 16);
}

__device__ __forceinline__ void gload_lds16(const u16* g, u16* l) {
  __builtin_amdgcn_global_load_lds(
      (const __attribute__((address_space(1))) u32*)g,
      (__attribute__((address_space(3))) u32*)l, 16, 0, 0);
}

// ---------------------------------------------------------------------------
// fp32 -> bf16 conversion for all four 512x1024 weight matrices in one launch
// ---------------------------------------------------------------------------
__global__ __launch_bounds__(256) void k_cvt4(
    const float* __restrict__ s0, const float* __restrict__ s1,
    const float* __restrict__ s2, const float* __restrict__ s3,
    u16* __restrict__ d0, u16* __restrict__ d1, u16* __restrict__ d2,
    u16* __restrict__ d3) {
  int gid = blockIdx.x * 256 + threadIdx.x;
  int which = gid >> 17;                // 131072 threads per matrix
  int loc = (gid & 131071) * 4;
  const float* s = which == 0 ? s0 : which == 1 ? s1 : which == 2 ? s2 : s3;
  u16* d = which == 0 ? d0 : which == 1 ? d1 : which == 2 ? d2 : d3;
  float4 v = *(const float4*)(s + loc);
  u32 lo = (u32)f2bf(v.x) | ((u32)f2bf(v.y) << 16);
  u32 hi = (u32)f2bf(v.z) | ((u32)f2bf(v.w) << 16);
  uint2 o; o.x = lo; o.y = hi;
  *(uint2*)(d + loc) = o;
}

// ---------------------------------------------------------------------------
// Fused: x [B,1024,64,64] fp32 -> xT [B,4096,1024] bf16 (transpose+cast)
//                              -> xpT [B,1024,1024] bf16 (2x2 maxpool + T)
// ---------------------------------------------------------------------------
__global__ __launch_bounds__(256) void k_transpose_pool(
    const float* __restrict__ x, u16* __restrict__ xT, u16* __restrict__ xpT) {
  __shared__ u16 lds[128 * 64];
  const int t = threadIdx.x;
  const int c0 = blockIdx.x * 64;
  const int by = blockIdx.y;        // h0 = by*2
  const int b = blockIdx.z;

  {
    const int nf = (t & 31) * 4;
    const int swz = 8 * (t & 7);
    const float* xb =
        x + ((size_t)(b * 1024 + c0 + (t >> 5)) * 4096) + by * 128 + nf;
#pragma unroll
    for (int u = 0; u < 8; ++u) {
      const int c_l = (t >> 5) + 8 * u;
      float4 v = *(const float4*)(xb + (size_t)(8 * u) * 4096);
      const int col = c_l ^ swz;
      lds[(nf + 0) * 64 + col] = f2bf(v.x);
      lds[(nf + 1) * 64 + col] = f2bf(v.y);
      lds[(nf + 2) * 64 + col] = f2bf(v.z);
      lds[(nf + 3) * 64 + col] = f2bf(v.w);
    }
  }
  __syncthreads();
  {
#pragma unroll
    for (int v = 0; v < 4; ++v) {
      const int idx = t + 256 * v;
      const int n_l = idx >> 3;
      const int cb = (idx & 7) * 8;
      const int col = cb ^ (8 * ((n_l >> 2) & 7));
      bf16x8 d = *(const bf16x8*)&lds[n_l * 64 + col];
      *(bf16x8*)&xT[((size_t)b * 4096 + by * 128 + n_l) * 1024 + c0 + cb] = d;
    }
  }
  {
    const int m_w = t >> 3;
    const int cb = (t & 7) * 8;
    const int na = 2 * m_w, nb = na + 1, nc = na + 64, nd = na + 65;
    bf16x8 va = *(const bf16x8*)&lds[na * 64 + (cb ^ (8 * ((na >> 2) & 7)))];
    bf16x8 vb = *(const bf16x8*)&lds[nb * 64 + (cb ^ (8 * ((nb >> 2) & 7)))];
    bf16x8 vc = *(const bf16x8*)&lds[nc * 64 + (cb ^ (8 * ((nc >> 2) & 7)))];
    bf16x8 vd = *(const bf16x8*)&lds[nd * 64 + (cb ^ (8 * ((nd >> 2) & 7)))];
    bf16x8 o;
#pragma unroll
    for (int j = 0; j < 8; ++j) {
      float m = fmaxf(fmaxf(bf2f((u16)va[j]), bf2f((u16)vb[j])),
                      fmaxf(bf2f((u16)vc[j]), bf2f((u16)vd[j])));
      o[j] = (short)f2bf(m);
    }
    *(bf16x8*)&xpT[((size_t)b * 1024 + by * 32 + m_w) * 1024 + c0 + cb] = o;
  }
}

// ---------------------------------------------------------------------------
// 128x128 NT GEMM (round-2 winner): for small-grid GEMMs (phi, g).
// ---------------------------------------------------------------------------
template <int BIAS_MODE>  // 0 none, 1 row (bias[i]), 2 col (bias[j])
__global__ __launch_bounds__(256, 2) void gemm_nt(
    const u16* __restrict__ A, long aBS, const u16* __restrict__ Bm, long bBS,
    u16* __restrict__ Cm, long cBS, const float* __restrict__ bias, int N,
    int K, float scale) {
  __shared__ u16 Alds[2][128 * 32];
  __shared__ u16 Blds[2][128 * 32];
  const int t = threadIdx.x;
  const int b = blockIdx.z;
  const int bm = blockIdx.y, bn = blockIdx.x;
  const u16* Ab = A + (size_t)b * aBS + (size_t)bm * 128 * K;
  const u16* Bb = Bm + (size_t)b * bBS + (size_t)bn * 128 * K;

  const int lane = t & 63;
  const int w = t >> 6;
  const int wrow = w >> 1, wcol = w & 1;
  const int lr = lane & 15;
  const int kg = lane >> 4;

  f32x4 acc[4][4] = {};

  const int e0 = t * 8;
  const int r0 = e0 >> 5;
  const int k0i = e0 & 31;
  const int steps = K >> 5;

#define STAGE(buf, ks)                                                   \
  do {                                                                   \
    const int kb = (ks) * 32;                                            \
    gload_lds16(Ab + (size_t)r0 * K + kb + k0i, &Alds[buf][e0]);         \
    gload_lds16(Ab + (size_t)(r0 + 64) * K + kb + k0i,                   \
                &Alds[buf][e0 + 2048]);                                  \
    gload_lds16(Bb + (size_t)r0 * K + kb + k0i, &Blds[buf][e0]);         \
    gload_lds16(Bb + (size_t)(r0 + 64) * K + kb + k0i,                   \
                &Blds[buf][e0 + 2048]);                                  \
  } while (0)

  STAGE(0, 0);
  for (int ks = 0; ks < steps; ++ks) {
    const int cur = ks & 1;
    __syncthreads();
    if (ks + 1 < steps) STAGE(cur ^ 1, ks + 1);
    bf16x8 af[4], bfr[4];
#pragma unroll
    for (int i = 0; i < 4; ++i) {
      af[i] =
          *(const bf16x8*)&Alds[cur][(wrow * 64 + i * 16 + lr) * 32 + kg * 8];
      bfr[i] =
          *(const bf16x8*)&Blds[cur][(wcol * 64 + i * 16 + lr) * 32 + kg * 8];
    }
#pragma unroll
    for (int i = 0; i < 4; ++i)
#pragma unroll
      for (int j = 0; j < 4; ++j)
        acc[i][j] = __builtin_amdgcn_mfma_f32_16x16x32_bf16(af[i], bfr[j],
                                                            acc[i][j], 0, 0, 0);
  }
#undef STAGE

  u16* Cb = Cm + (size_t)b * cBS;
#pragma unroll
  for (int i = 0; i < 4; ++i) {
#pragma unroll
    for (int j = 0; j < 4; ++j) {
      int row0 = bm * 128 + wrow * 64 + i * 16 + kg * 4;
      int col = bn * 128 + wcol * 64 + j * 16 + lr;
      float bj = (BIAS_MODE == 2) ? bias[col] : 0.f;
#pragma unroll
      for (int r = 0; r < 4; ++r) {
        float v = acc[i][j][r] * scale;
        if (BIAS_MODE == 1) v += bias[row0 + r];
        if (BIAS_MODE == 2) v += bj;
        Cb[(size_t)(row0 + r) * N + col] = f2bf(v);
      }
    }
  }
}

// ---------------------------------------------------------------------------
// 256x256 8-phase NT GEMM (big-grid GEMMs). Exact round-3-verified shape;
// __launch_bounds__(512, 2): 2 waves/EU is the LDS-bound occupancy (128 KiB
// -> 1 block/CU); pins regalloc at the 256-VGPR budget so the 128-VGPR
// accumulator can never spill (round-4 failure: VGPR_Count=96 => scratch).
// ---------------------------------------------------------------------------
template <int BIAS_MODE>  // 0 none, 1 row (bias[i]), 2 col (bias[j])
__global__ __launch_bounds__(512, 2) void gemm256(
    const u16* __restrict__ A, long aBS, const u16* __restrict__ Bm, long bBS,
    u16* __restrict__ Cm, long cBS, const float* __restrict__ bias, int N,
    int K, float scale) {
  __shared__ u16 ALDS[2][16384];
  __shared__ u16 BLDS[2][16384];
  const int t = threadIdx.x;
  u32 gx = gridDim.x, gy = gridDim.y;
  u32 nwg = gx * gy * gridDim.z;
  u32 wg = blockIdx.x + gx * (blockIdx.y + gy * blockIdx.z);
  u32 swz = (wg & 7) * (nwg >> 3) + (wg >> 3);
  const int bn = swz % gx;
  u32 tmp = swz / gx;
  const int bm = tmp % gy;
  const int b = tmp / gy;

  const u16* Agb = A + (size_t)b * aBS + (size_t)bm * 256 * K;
  const u16* Bgb = Bm + (size_t)b * bBS + (size_t)bn * 256 * K;

  const int lane = t & 63;
  const int wid = t >> 6;
  const int wr = wid >> 2;
  const int wc = wid & 3;
  const int lr = lane & 15;
  const int kg = (lane >> 4) & 3;
  const int T = K >> 6;

  f32x4 acc[8][4] = {};

#define STAGE_G(LDSARR, GB, h, ktn)                                          \
  if ((ktn) < T) {                                                           \
    {                                                                        \
      const int r = t >> 3;                                                  \
      gload_lds16(GB + (size_t)((h)*128 + r) * K + (size_t)(ktn)*64 +        \
                      (((t & 7) ^ (r & 7)) * 8),                             \
                  &LDSARR[(ktn) & 1][(h)*8192 + t * 8]);                     \
    }                                                                        \
    {                                                                        \
      const int idx = 512 + t;                                               \
      const int r = idx >> 3;                                                \
      gload_lds16(GB + (size_t)((h)*128 + r) * K + (size_t)(ktn)*64 +        \
                      (((t & 7) ^ (r & 7)) * 8),                             \
                  &LDSARR[(ktn) & 1][(h)*8192 + idx * 8]);                   \
    }                                                                        \
  }
#define STAGE_A(h, ktn) STAGE_G(ALDS, Agb, h, ktn)
#define STAGE_B(h, ktn) STAGE_G(BLDS, Bgb, h, ktn)

#define LDA4(mh, kk)                                                         \
  _Pragma("unroll") for (int m2 = 0; m2 < 4; ++m2) {                         \
    const int row = wr * 128 + ((mh)*4 + m2) * 16 + lr;                      \
    aF[m2] = *(const bf16x8*)&ALDS[cb][row * 64 +                            \
                                       ((((kk)*4 + kg) ^ (lr & 7)) * 8)];    \
  }
#define LDB4(kk)                                                             \
  _Pragma("unroll") for (int n = 0; n < 4; ++n) {                            \
    const int row = wc * 64 + n * 16 + lr;                                   \
    bF[n] = *(const bf16x8*)&BLDS[cb][row * 64 +                             \
                                      ((((kk)*4 + kg) ^ (lr & 7)) * 8)];     \
  }
#define MFMA16(M0)                                                           \
  __builtin_amdgcn_s_setprio(1);                                             \
  _Pragma("unroll") for (int n = 0; n < 4; ++n) {                            \
    acc[(M0) + 0][n] = __builtin_amdgcn_mfma_f32_16x16x32_bf16(              \
        aF[0], bF[n], acc[(M0) + 0][n], 0, 0, 0);                            \
    acc[(M0) + 1][n] = __builtin_amdgcn_mfma_f32_16x16x32_bf16(              \
        aF[1], bF[n], acc[(M0) + 1][n], 0, 0, 0);                            \
    acc[(M0) + 2][n] = __builtin_amdgcn_mfma_f32_16x16x32_bf16(              \
        aF[2], bF[n], acc[(M0) + 2][n], 0, 0, 0);                            \
    acc[(M0) + 3][n] = __builtin_amdgcn_mfma_f32_16x16x32_bf16(              \
        aF[3], bF[n], acc[(M0) + 3][n], 0, 0, 0);                            \
  }                                                                          \
  __builtin_amdgcn_s_setprio(0);
#define CFENCE asm volatile("" ::: "memory")

  STAGE_B(0, 0);
  STAGE_B(1, 0);
  STAGE_A(0, 0);
  STAGE_A(1, 0);
  STAGE_B(0, 1);

  for (int kt = 0; kt < T; ++kt) {
    const int cb = kt & 1;
    bf16x8 aF[4], bF[4];
    asm volatile("s_waitcnt vmcnt(2)" ::: "memory");
    __builtin_amdgcn_s_barrier();
    STAGE_B(1, kt + 1);
    LDB4(0);
    LDA4(0, 0);
    MFMA16(0);
    CFENCE;
    __builtin_amdgcn_s_barrier();
    STAGE_A(0, kt + 1);
    LDA4(1, 0);
    MFMA16(4);
    CFENCE;
    __builtin_amdgcn_s_barrier();
    STAGE_A(1, kt + 1);
    LDB4(1);
    LDA4(0, 1);
    MFMA16(0);
    CFENCE;
    __builtin_amdgcn_s_barrier();
    STAGE_B(0, kt + 2);
    LDA4(1, 1);
    MFMA16(4);
    CFENCE;
    __builtin_amdgcn_s_barrier();
  }

  u16* Cb = Cm + (size_t)b * cBS;
#pragma unroll
  for (int m = 0; m < 8; ++m) {
    const int row0 = bm * 256 + wr * 128 + m * 16 + kg * 4;
#pragma unroll
    for (int n = 0; n < 4; ++n) {
      const int col = bn * 256 + wc * 64 + n * 16 + lr;
      float bj = (BIAS_MODE == 2) ? bias[col] : 0.f;
#pragma unroll
      for (int r = 0; r < 4; ++r) {
        float v = acc[m][n][r] * scale;
        if (BIAS_MODE == 1) v += bias[row0 + r];
        if (BIAS_MODE == 2) v += bj;
        Cb[(size_t)(row0 + r) * N + col] = f2bf(v);
      }
    }
  }
#undef STAGE_G
#undef STAGE_A
#undef STAGE_B
#undef LDA4
#undef LDB4
#undef MFMA16
#undef CFENCE
}

// ---------------------------------------------------------------------------
// Row softmax, in place. Rows of 1024 bf16, one wave per row, 4 rows/block.
// ---------------------------------------------------------------------------
__global__ __launch_bounds__(256) void k_softmax(u16* __restrict__ S) {
  const int t = threadIdx.x;
  const int lane = t & 63;
  const size_t row = (size_t)blockIdx.x * 4 + (t >> 6);
  u16* p = S + row * 1024 + lane * 16;
  uint4 d0 = *(const uint4*)p;
  uint4 d1 = *(const uint4*)(p + 8);
  u32 u[8] = {d0.x, d0.y, d0.z, d0.w, d1.x, d1.y, d1.z, d1.w};
  float v[16];
#pragma unroll
  for (int i = 0; i < 8; ++i) {
    v[2 * i] = bf2f((u16)(u[i] & 0xffff));
    v[2 * i + 1] = bf2f((u16)(u[i] >> 16));
  }
  float m = v[0];
#pragma unroll
  for (int i = 1; i < 16; ++i) m = fmaxf(m, v[i]);
  for (int o = 32; o > 0; o >>= 1) m = fmaxf(m, __shfl_xor(m, o));
  const float LOG2E = 1.44269504088896f;
  float s = 0.f;
#pragma unroll
  for (int i = 0; i < 16; ++i) {
    v[i] = exp2f((v[i] - m) * LOG2E);
    s += v[i];
  }
  for (int o = 32; o > 0; o >>= 1) s += __shfl_xor(s, o);
  float inv = 1.0f / s;
#pragma unroll
  for (int i = 0; i < 8; ++i)
    u[i] = (u32)f2bf(v[2 * i] * inv) | ((u32)f2bf(v[2 * i + 1] * inv) << 16);
  uint4 o0; o0.x = u[0]; o0.y = u[1]; o0.z = u[2]; o0.w = u[3];
  uint4 o1; o1.x = u[4]; o1.y = u[5]; o1.z = u[6]; o1.w = u[7];
  *(uint4*)p = o0;
  *(uint4*)(p + 8) = o1;
}

// ---------------------------------------------------------------------------
// BN stats: per channel o, sum & sumsq of z[b][o][n] over b,n. block per o.
// ---------------------------------------------------------------------------
__global__ __launch_bounds__(256) void k_stats(const u16* __restrict__ z,
                                               float2* __restrict__ stats) {
  const int o = blockIdx.x;
  const int t = threadIdx.x;
  float s = 0.f, q = 0.f;
  for (int b = 0; b < 8; ++b) {
    const u16* p = z + ((size_t)b * 1024 + o) * 4096;
    for (int i = t * 4; i < 4096; i += 1024) {
      uint2 d = *(const uint2*)(p + i);
      float a0 = bf2f((u16)(d.x & 0xffff)), a1 = bf2f((u16)(d.x >> 16));
      float a2 = bf2f((u16)(d.y & 0xffff)), a3 = bf2f((u16)(d.y >> 16));
      s += a0 + a1 + a2 + a3;
      q += a0 * a0 + a1 * a1 + a2 * a2 + a3 * a3;
    }
  }
  for (int o2 = 32; o2 > 0; o2 >>= 1) {
    s += __shfl_xor(s, o2);
    q += __shfl_xor(q, o2);
  }
  __shared__ float2 red[4];
  if ((t & 63) == 0) red[t >> 6] = make_float2(s, q);
  __syncthreads();
  if (t == 0) {
    float S_ = 0.f, Q_ = 0.f;
    for (int i = 0; i < 4; ++i) { S_ += red[i].x; Q_ += red[i].y; }
    stats[o] = make_float2(S_, Q_);
  }
}

// ---------------------------------------------------------------------------
// BN apply + residual: out = x + (z-mean)*rsqrt(var+eps)*gamma + beta
// ---------------------------------------------------------------------------
__global__ __launch_bounds__(256) void k_apply(
    const float* __restrict__ x, const u16* __restrict__ z,
    const float2* __restrict__ stats, const float* __restrict__ gamma,
    const float* __restrict__ beta, float* __restrict__ out) {
  size_t i4 = (size_t)blockIdx.x * 256 + threadIdx.x;
  size_t e = i4 * 4;
  int c = (int)((e >> 12) & 1023);
  float2 st = stats[c];
  const float cnt = 1.0f / 32768.0f;
  float mean = st.x * cnt;
  float var = st.y * cnt - mean * mean;
  float g = rsqrtf(var + 1e-5f) * gamma[c];
  float sh = beta[c] - mean * g;
  float4 xv = *(const float4*)(x + e);
  uint2 zd = *(const uint2*)(z + e);
  float z0 = bf2f((u16)(zd.x & 0xffff)), z1 = bf2f((u16)(zd.x >> 16));
  float z2 = bf2f((u16)(zd.y & 0xffff)), z3 = bf2f((u16)(zd.y >> 16));
  float4 ov;
  ov.x = xv.x + z0 * g + sh;
  ov.y = xv.y + z1 * g + sh;
  ov.z = xv.z + z2 * g + sh;
  ov.w = xv.w + z3 * g + sh;
  *(float4*)(out + e) = ov;
}

// ---------------------------------------------------------------------------
extern "C" void kernel_launch(void* const* d_in, const int* in_sizes, int n_in,
                              void* d_out, int out_size, void* d_ws,
                              size_t ws_size, hipStream_t stream) {
  const float* x = (const float*)d_in[0];
  const float* theta_w = (const float*)d_in[1];
  const float* theta_b = (const float*)d_in[2];
  const float* phi_w = (const float*)d_in[3];
  const float* phi_b = (const float*)d_in[4];
  const float* g_w = (const float*)d_in[5];
  const float* g_b = (const float*)d_in[6];
  const float* wz_w = (const float*)d_in[7];
  const float* wz_b = (const float*)d_in[8];
  const float* gamma = (const float*)d_in[9];
  const float* beta = (const float*)d_in[10];
  float* out = (float*)d_out;

  char* w = (char*)d_ws;
  const size_t MiB = (size_t)1 << 20;
  u16* WT = (u16*)(w + 0 * MiB);
  u16* WP = (u16*)(w + 1 * MiB);
  u16* WG = (u16*)(w + 2 * MiB);
  u16* WZ = (u16*)(w + 3 * MiB);
  u16* XT = (u16*)(w + 4 * MiB);      // [8][4096][1024] 64 MiB
  u16* XPT = (u16*)(w + 68 * MiB);    // [8][1024][1024] 16 MiB
  u16* THETA = (u16*)(w + 84 * MiB);  // [8][4096][512]  32 MiB
  u16* PHI = (u16*)(w + 116 * MiB);   // [8][1024][512]   8 MiB
  u16* G = (u16*)(w + 124 * MiB);     // [8][512][1024]   8 MiB
  u16* S = XT;                        // reuse xT region (dead after theta GEMM)
  u16* YT = (u16*)(w + 132 * MiB);    // [8][4096][512]  32 MiB
  u16* Z = S;                         // reuse again (P dead after yT GEMM)
  float2* stats = (float2*)(w + 164 * MiB);

  // weights -> bf16 (one launch)
  k_cvt4<<<2048, 256, 0, stream>>>(theta_w, phi_w, g_w, wz_w, WT, WP, WG, WZ);
  // x -> xT, xpT
  k_transpose_pool<<<dim3(16, 32, 8), 256, 0, stream>>>(x, XT, XPT);
  // thetaT[n,ci] = xT @ theta_w^T + theta_b  (batch folded into M=32768)
  gemm256<2><<<dim3(2, 128, 1), 512, 0, stream>>>(
      XT, 0, WT, 0, THETA, 0, theta_b, 512, 1024, 1.0f);
  // phiT[m,ci]  (128^2 tile: small-grid GEMM)
  gemm_nt<2><<<dim3(4, 8, 8), 256, 0, stream>>>(
      XPT, (long)1024 * 1024, WP, 0, PHI, (long)1024 * 512, phi_b, 512, 1024,
      1.0f);
  // g[ci,m]  (128^2 tile: small-grid GEMM)
  gemm_nt<1><<<dim3(8, 4, 8), 256, 0, stream>>>(
      WG, 0, XPT, (long)1024 * 1024, G, (long)512 * 1024, g_b, 1024, 1024,
      1.0f);
  // S[n,m] = thetaT . phiT^T * scale
  gemm256<0><<<dim3(4, 16, 8), 512, 0, stream>>>(
      THETA, (long)4096 * 512, PHI, (long)1024 * 512, S, (long)4096 * 1024,
      nullptr, 1024, 512, 0.04419417382415922f);
  // softmax rows (in place -> P)
  k_softmax<<<8192, 256, 0, stream>>>(S);
  // yT[n,ci] = P . g^T
  gemm256<0><<<dim3(2, 16, 8), 512, 0, stream>>>(
      S, (long)4096 * 1024, G, (long)512 * 1024, YT, (long)4096 * 512, nullptr,
      512, 1024, 1.0f);
  // z[o,n] = wz . yT^T + wz_b   (bias over row=o)
  gemm256<1><<<dim3(16, 4, 8), 512, 0, stream>>>(
      WZ, 0, YT, (long)4096 * 512, Z, (long)1024 * 4096, wz_b, 4096, 512,
      1.0f);
  // BN stats + apply + residual
  k_stats<<<1024, 256, 0, stream>>>(Z, stats);
  k_apply<<<32768, 256, 0, stream>>>(x, Z, stats, gamma, beta, out);

  (void)in_sizes; (void)n_in; (void)out_size; (void)ws_size;
}

// Round 6
// 549.128 us; speedup vs baseline: 1.4600x; 1.0680x over previous
//
#include <hip/hip_runtime.h>

typedef unsigned short u16;
typedef unsigned int u32;
typedef __attribute__((ext_vector_type(8))) short bf16x8;
typedef __attribute__((ext_vector_type(4))) float f32x4;

__device__ __forceinline__ u16 f2bf(float f) {
  u32 u = __builtin_bit_cast(u32, f);
  u = u + 0x7FFFu + ((u >> 16) & 1u);
  return (u16)(u >> 16);
}
__device__ __forceinline__ float bf2f(u16 s) {
  return __builtin_bit_cast(float, (u32)s << 16);
}

__device__ __forceinline__ void gload_lds16(const u16* g, u16* l) {
  __builtin_amdgcn_global_load_lds(
      (const __attribute__((address_space(1))) u32*)g,
      (__attribute__((address_space(3))) u32*)l, 16, 0, 0);
}

// ---------------------------------------------------------------------------
// fp32 -> bf16 conversion for all four 512x1024 weight matrices in one launch
// ---------------------------------------------------------------------------
__global__ __launch_bounds__(256) void k_cvt4(
    const float* __restrict__ s0, const float* __restrict__ s1,
    const float* __restrict__ s2, const float* __restrict__ s3,
    u16* __restrict__ d0, u16* __restrict__ d1, u16* __restrict__ d2,
    u16* __restrict__ d3) {
  int gid = blockIdx.x * 256 + threadIdx.x;
  int which = gid >> 17;                // 131072 threads per matrix
  int loc = (gid & 131071) * 4;
  const float* s = which == 0 ? s0 : which == 1 ? s1 : which == 2 ? s2 : s3;
  u16* d = which == 0 ? d0 : which == 1 ? d1 : which == 2 ? d2 : d3;
  float4 v = *(const float4*)(s + loc);
  u32 lo = (u32)f2bf(v.x) | ((u32)f2bf(v.y) << 16);
  u32 hi = (u32)f2bf(v.z) | ((u32)f2bf(v.w) << 16);
  uint2 o; o.x = lo; o.y = hi;
  *(uint2*)(d + loc) = o;
}

// ---------------------------------------------------------------------------
// Fused: x [B,1024,64,64] fp32 -> xT [B,4096,1024] bf16 (transpose+cast)
//                              -> xpT [B,1024,1024] bf16 (2x2 maxpool + T)
// ---------------------------------------------------------------------------
__global__ __launch_bounds__(256) void k_transpose_pool(
    const float* __restrict__ x, u16* __restrict__ xT, u16* __restrict__ xpT) {
  __shared__ u16 lds[128 * 64];
  const int t = threadIdx.x;
  const int c0 = blockIdx.x * 64;
  const int by = blockIdx.y;        // h0 = by*2
  const int b = blockIdx.z;

  {
    const int nf = (t & 31) * 4;
    const int swz = 8 * (t & 7);
    const float* xb =
        x + ((size_t)(b * 1024 + c0 + (t >> 5)) * 4096) + by * 128 + nf;
#pragma unroll
    for (int u = 0; u < 8; ++u) {
      const int c_l = (t >> 5) + 8 * u;
      float4 v = *(const float4*)(xb + (size_t)(8 * u) * 4096);
      const int col = c_l ^ swz;
      lds[(nf + 0) * 64 + col] = f2bf(v.x);
      lds[(nf + 1) * 64 + col] = f2bf(v.y);
      lds[(nf + 2) * 64 + col] = f2bf(v.z);
      lds[(nf + 3) * 64 + col] = f2bf(v.w);
    }
  }
  __syncthreads();
  {
#pragma unroll
    for (int v = 0; v < 4; ++v) {
      const int idx = t + 256 * v;
      const int n_l = idx >> 3;
      const int cb = (idx & 7) * 8;
      const int col = cb ^ (8 * ((n_l >> 2) & 7));
      bf16x8 d = *(const bf16x8*)&lds[n_l * 64 + col];
      *(bf16x8*)&xT[((size_t)b * 4096 + by * 128 + n_l) * 1024 + c0 + cb] = d;
    }
  }
  {
    const int m_w = t >> 3;
    const int cb = (t & 7) * 8;
    const int na = 2 * m_w, nb = na + 1, nc = na + 64, nd = na + 65;
    bf16x8 va = *(const bf16x8*)&lds[na * 64 + (cb ^ (8 * ((na >> 2) & 7)))];
    bf16x8 vb = *(const bf16x8*)&lds[nb * 64 + (cb ^ (8 * ((nb >> 2) & 7)))];
    bf16x8 vc = *(const bf16x8*)&lds[nc * 64 + (cb ^ (8 * ((nc >> 2) & 7)))];
    bf16x8 vd = *(const bf16x8*)&lds[nd * 64 + (cb ^ (8 * ((nd >> 2) & 7)))];
    bf16x8 o;
#pragma unroll
    for (int j = 0; j < 8; ++j) {
      float m = fmaxf(fmaxf(bf2f((u16)va[j]), bf2f((u16)vb[j])),
                      fmaxf(bf2f((u16)vc[j]), bf2f((u16)vd[j])));
      o[j] = (short)f2bf(m);
    }
    *(bf16x8*)&xpT[((size_t)b * 1024 + by * 32 + m_w) * 1024 + c0 + cb] = o;
  }
}

// ---------------------------------------------------------------------------
// Dual 128x128 NT GEMM: phi (blocks 0..255) + g (blocks 256..511) in ONE
// launch so both fill the chip (each alone = 256 blocks = half the CUs).
// phi: PHI[m,ci] = XPT[b]·WP^T + phi_b(col);  g: G[ci,m] = WG·XPT[b]^T + g_b(row)
// K = 1024 for both.
// ---------------------------------------------------------------------------
__global__ __launch_bounds__(256, 2) void gemm_dual(
    const u16* __restrict__ XPT, const u16* __restrict__ WP,
    const u16* __restrict__ WG, u16* __restrict__ PHI, u16* __restrict__ G,
    const float* __restrict__ phi_b, const float* __restrict__ g_b) {
  __shared__ u16 Alds[2][128 * 32];
  __shared__ u16 Blds[2][128 * 32];
  const int t = threadIdx.x;
  const int K = 1024;

  int id = blockIdx.x;
  const u16 *Ab, *Bb;
  u16* Cm;
  const float* bias;
  int N, bias_mode, bm, bn;
  if (id < 256) {  // phi
    bn = id & 3; bm = (id >> 2) & 7; const int b = id >> 5;
    Ab = XPT + (size_t)b * 1024 * 1024 + (size_t)bm * 128 * K;
    Bb = WP + (size_t)bn * 128 * K;
    Cm = PHI + (size_t)b * 1024 * 512;
    bias = phi_b; N = 512; bias_mode = 2;
  } else {  // g
    id -= 256;
    bn = id & 7; bm = (id >> 3) & 3; const int b = id >> 5;
    Ab = WG + (size_t)bm * 128 * K;
    Bb = XPT + (size_t)b * 1024 * 1024 + (size_t)bn * 128 * K;
    Cm = G + (size_t)b * 512 * 1024;
    bias = g_b; N = 1024; bias_mode = 1;
  }

  const int lane = t & 63;
  const int w = t >> 6;
  const int wrow = w >> 1, wcol = w & 1;
  const int lr = lane & 15;
  const int kg = lane >> 4;

  f32x4 acc[4][4] = {};

  const int e0 = t * 8;
  const int r0 = e0 >> 5;
  const int k0i = e0 & 31;
  const int steps = K >> 5;

#define STAGE(buf, ks)                                                   \
  do {                                                                   \
    const int kb = (ks) * 32;                                            \
    gload_lds16(Ab + (size_t)r0 * K + kb + k0i, &Alds[buf][e0]);         \
    gload_lds16(Ab + (size_t)(r0 + 64) * K + kb + k0i,                   \
                &Alds[buf][e0 + 2048]);                                  \
    gload_lds16(Bb + (size_t)r0 * K + kb + k0i, &Blds[buf][e0]);         \
    gload_lds16(Bb + (size_t)(r0 + 64) * K + kb + k0i,                   \
                &Blds[buf][e0 + 2048]);                                  \
  } while (0)

  STAGE(0, 0);
  for (int ks = 0; ks < steps; ++ks) {
    const int cur = ks & 1;
    __syncthreads();
    if (ks + 1 < steps) STAGE(cur ^ 1, ks + 1);
    bf16x8 af[4], bfr[4];
#pragma unroll
    for (int i = 0; i < 4; ++i) {
      af[i] =
          *(const bf16x8*)&Alds[cur][(wrow * 64 + i * 16 + lr) * 32 + kg * 8];
      bfr[i] =
          *(const bf16x8*)&Blds[cur][(wcol * 64 + i * 16 + lr) * 32 + kg * 8];
    }
#pragma unroll
    for (int i = 0; i < 4; ++i)
#pragma unroll
      for (int j = 0; j < 4; ++j)
        acc[i][j] = __builtin_amdgcn_mfma_f32_16x16x32_bf16(af[i], bfr[j],
                                                            acc[i][j], 0, 0, 0);
  }
#undef STAGE

#pragma unroll
  for (int i = 0; i < 4; ++i) {
#pragma unroll
    for (int j = 0; j < 4; ++j) {
      int row0 = bm * 128 + wrow * 64 + i * 16 + kg * 4;
      int col = bn * 128 + wcol * 64 + j * 16 + lr;
      float bj = (bias_mode == 2) ? bias[col] : 0.f;
#pragma unroll
      for (int r = 0; r < 4; ++r) {
        float v = acc[i][j][r];
        v += (bias_mode == 1) ? bias[row0 + r] : bj;
        Cm[(size_t)(row0 + r) * N + col] = f2bf(v);
      }
    }
  }
}

// ---------------------------------------------------------------------------
// 256x256 8-phase NT GEMM (big-grid GEMMs), stage-lead-fixed:
// ALL of tile kt+1's B1/A0/A1 stages issue at q0 (legal: their target
// regions' last readers precede the q0 barrier), B0(kt+2) at q3 ->
// stage leads 4,4,4,5 phases (was 2-4): covers ~900cy HBM latency so the
// per-K-tile vmcnt(2) no longer stalls. Tail: last iter waits vmcnt(0)
// (A1(T-1) would otherwise be un-drained at its q1 use).
// __launch_bounds__(512,2) pins regalloc (round-4 spill lesson).
// ---------------------------------------------------------------------------
template <int BIAS_MODE>  // 0 none, 1 row (bias[i]), 2 col (bias[j])
__global__ __launch_bounds__(512, 2) void gemm256(
    const u16* __restrict__ A, long aBS, const u16* __restrict__ Bm, long bBS,
    u16* __restrict__ Cm, long cBS, const float* __restrict__ bias, int N,
    int K, float scale) {
  __shared__ u16 ALDS[2][16384];
  __shared__ u16 BLDS[2][16384];
  const int t = threadIdx.x;
  u32 gx = gridDim.x, gy = gridDim.y;
  u32 nwg = gx * gy * gridDim.z;
  u32 wg = blockIdx.x + gx * (blockIdx.y + gy * blockIdx.z);
  u32 swz = (wg & 7) * (nwg >> 3) + (wg >> 3);
  const int bn = swz % gx;
  u32 tmp = swz / gx;
  const int bm = tmp % gy;
  const int b = tmp / gy;

  const u16* Agb = A + (size_t)b * aBS + (size_t)bm * 256 * K;
  const u16* Bgb = Bm + (size_t)b * bBS + (size_t)bn * 256 * K;

  const int lane = t & 63;
  const int wid = t >> 6;
  const int wr = wid >> 2;
  const int wc = wid & 3;
  const int lr = lane & 15;
  const int kg = (lane >> 4) & 3;
  const int T = K >> 6;

  f32x4 acc[8][4] = {};

#define STAGE_G(LDSARR, GB, h, ktn)                                          \
  if ((ktn) < T) {                                                           \
    {                                                                        \
      const int r = t >> 3;                                                  \
      gload_lds16(GB + (size_t)((h)*128 + r) * K + (size_t)(ktn)*64 +        \
                      (((t & 7) ^ (r & 7)) * 8),                             \
                  &LDSARR[(ktn) & 1][(h)*8192 + t * 8]);                     \
    }                                                                        \
    {                                                                        \
      const int idx = 512 + t;                                               \
      const int r = idx >> 3;                                                \
      gload_lds16(GB + (size_t)((h)*128 + r) * K + (size_t)(ktn)*64 +        \
                      (((t & 7) ^ (r & 7)) * 8),                             \
                  &LDSARR[(ktn) & 1][(h)*8192 + idx * 8]);                   \
    }                                                                        \
  }
#define STAGE_A(h, ktn) STAGE_G(ALDS, Agb, h, ktn)
#define STAGE_B(h, ktn) STAGE_G(BLDS, Bgb, h, ktn)

#define LDA4(mh, kk)                                                         \
  _Pragma("unroll") for (int m2 = 0; m2 < 4; ++m2) {                         \
    const int row = wr * 128 + ((mh)*4 + m2) * 16 + lr;                      \
    aF[m2] = *(const bf16x8*)&ALDS[cb][row * 64 +                            \
                                       ((((kk)*4 + kg) ^ (lr & 7)) * 8)];    \
  }
#define LDB4(kk)                                                             \
  _Pragma("unroll") for (int n = 0; n < 4; ++n) {                            \
    const int row = wc * 64 + n * 16 + lr;                                   \
    bF[n] = *(const bf16x8*)&BLDS[cb][row * 64 +                             \
                                      ((((kk)*4 + kg) ^ (lr & 7)) * 8)];     \
  }
#define MFMA16(M0)                                                           \
  __builtin_amdgcn_s_setprio(1);                                             \
  _Pragma("unroll") for (int n = 0; n < 4; ++n) {                            \
    acc[(M0) + 0][n] = __builtin_amdgcn_mfma_f32_16x16x32_bf16(              \
        aF[0], bF[n], acc[(M0) + 0][n], 0, 0, 0);                            \
    acc[(M0) + 1][n] = __builtin_amdgcn_mfma_f32_16x16x32_bf16(              \
        aF[1], bF[n], acc[(M0) + 1][n], 0, 0, 0);                            \
    acc[(M0) + 2][n] = __builtin_amdgcn_mfma_f32_16x16x32_bf16(              \
        aF[2], bF[n], acc[(M0) + 2][n], 0, 0, 0);                            \
    acc[(M0) + 3][n] = __builtin_amdgcn_mfma_f32_16x16x32_bf16(              \
        aF[3], bF[n], acc[(M0) + 3][n], 0, 0, 0);                            \
  }                                                                          \
  __builtin_amdgcn_s_setprio(0);
#define CFENCE asm volatile("" ::: "memory")

  STAGE_B(0, 0);
  STAGE_B(1, 0);
  STAGE_A(0, 0);
  STAGE_A(1, 0);
  STAGE_B(0, 1);

  for (int kt = 0; kt < T; ++kt) {
    const int cb = kt & 1;
    bf16x8 aF[4], bF[4];
    // ---- q0 ----
    if (kt + 1 < T) {
      asm volatile("s_waitcnt vmcnt(2)" ::: "memory");
    } else {
      asm volatile("s_waitcnt vmcnt(0)" ::: "memory");
    }
    __builtin_amdgcn_s_barrier();
    STAGE_B(1, kt + 1);
    STAGE_A(0, kt + 1);
    STAGE_A(1, kt + 1);
    LDB4(0);
    LDA4(0, 0);
    MFMA16(0);
    CFENCE;
    __builtin_amdgcn_s_barrier();
    // ---- q1 ----
    LDA4(1, 0);
    MFMA16(4);
    CFENCE;
    __builtin_amdgcn_s_barrier();
    // ---- q2 ----
    LDB4(1);
    LDA4(0, 1);
    MFMA16(0);
    CFENCE;
    __builtin_amdgcn_s_barrier();
    // ---- q3 ----
    STAGE_B(0, kt + 2);
    LDA4(1, 1);
    MFMA16(4);
    CFENCE;
    __builtin_amdgcn_s_barrier();
  }

  u16* Cb = Cm + (size_t)b * cBS;
#pragma unroll
  for (int m = 0; m < 8; ++m) {
    const int row0 = bm * 256 + wr * 128 + m * 16 + kg * 4;
#pragma unroll
    for (int n = 0; n < 4; ++n) {
      const int col = bn * 256 + wc * 64 + n * 16 + lr;
      float bj = (BIAS_MODE == 2) ? bias[col] : 0.f;
#pragma unroll
      for (int r = 0; r < 4; ++r) {
        float v = acc[m][n][r] * scale;
        if (BIAS_MODE == 1) v += bias[row0 + r];
        if (BIAS_MODE == 2) v += bj;
        Cb[(size_t)(row0 + r) * N + col] = f2bf(v);
      }
    }
  }
#undef STAGE_G
#undef STAGE_A
#undef STAGE_B
#undef LDA4
#undef LDB4
#undef MFMA16
#undef CFENCE
}

// ---------------------------------------------------------------------------
// Row softmax, in place. Rows of 1024 bf16, one wave per row, 4 rows/block.
// ---------------------------------------------------------------------------
__global__ __launch_bounds__(256) void k_softmax(u16* __restrict__ S) {
  const int t = threadIdx.x;
  const int lane = t & 63;
  const size_t row = (size_t)blockIdx.x * 4 + (t >> 6);
  u16* p = S + row * 1024 + lane * 16;
  uint4 d0 = *(const uint4*)p;
  uint4 d1 = *(const uint4*)(p + 8);
  u32 u[8] = {d0.x, d0.y, d0.z, d0.w, d1.x, d1.y, d1.z, d1.w};
  float v[16];
#pragma unroll
  for (int i = 0; i < 8; ++i) {
    v[2 * i] = bf2f((u16)(u[i] & 0xffff));
    v[2 * i + 1] = bf2f((u16)(u[i] >> 16));
  }
  float m = v[0];
#pragma unroll
  for (int i = 1; i < 16; ++i) m = fmaxf(m, v[i]);
  for (int o = 32; o > 0; o >>= 1) m = fmaxf(m, __shfl_xor(m, o));
  const float LOG2E = 1.44269504088896f;
  float s = 0.f;
#pragma unroll
  for (int i = 0; i < 16; ++i) {
    v[i] = exp2f((v[i] - m) * LOG2E);
    s += v[i];
  }
  for (int o = 32; o > 0; o >>= 1) s += __shfl_xor(s, o);
  float inv = 1.0f / s;
#pragma unroll
  for (int i = 0; i < 8; ++i)
    u[i] = (u32)f2bf(v[2 * i] * inv) | ((u32)f2bf(v[2 * i + 1] * inv) << 16);
  uint4 o0; o0.x = u[0]; o0.y = u[1]; o0.z = u[2]; o0.w = u[3];
  uint4 o1; o1.x = u[4]; o1.y = u[5]; o1.z = u[6]; o1.w = u[7];
  *(uint4*)p = o0;
  *(uint4*)(p + 8) = o1;
}

// ---------------------------------------------------------------------------
// BN stats: per channel o, sum & sumsq of z[b][o][n] over b,n. block per o.
// ---------------------------------------------------------------------------
__global__ __launch_bounds__(256) void k_stats(const u16* __restrict__ z,
                                               float2* __restrict__ stats) {
  const int o = blockIdx.x;
  const int t = threadIdx.x;
  float s = 0.f, q = 0.f;
  for (int b = 0; b < 8; ++b) {
    const u16* p = z + ((size_t)b * 1024 + o) * 4096;
    for (int i = t * 4; i < 4096; i += 1024) {
      uint2 d = *(const uint2*)(p + i);
      float a0 = bf2f((u16)(d.x & 0xffff)), a1 = bf2f((u16)(d.x >> 16));
      float a2 = bf2f((u16)(d.y & 0xffff)), a3 = bf2f((u16)(d.y >> 16));
      s += a0 + a1 + a2 + a3;
      q += a0 * a0 + a1 * a1 + a2 * a2 + a3 * a3;
    }
  }
  for (int o2 = 32; o2 > 0; o2 >>= 1) {
    s += __shfl_xor(s, o2);
    q += __shfl_xor(q, o2);
  }
  __shared__ float2 red[4];
  if ((t & 63) == 0) red[t >> 6] = make_float2(s, q);
  __syncthreads();
  if (t == 0) {
    float S_ = 0.f, Q_ = 0.f;
    for (int i = 0; i < 4; ++i) { S_ += red[i].x; Q_ += red[i].y; }
    stats[o] = make_float2(S_, Q_);
  }
}

// ---------------------------------------------------------------------------
// BN apply + residual: out = x + (z-mean)*rsqrt(var+eps)*gamma + beta
// ---------------------------------------------------------------------------
__global__ __launch_bounds__(256) void k_apply(
    const float* __restrict__ x, const u16* __restrict__ z,
    const float2* __restrict__ stats, const float* __restrict__ gamma,
    const float* __restrict__ beta, float* __restrict__ out) {
  size_t i4 = (size_t)blockIdx.x * 256 + threadIdx.x;
  size_t e = i4 * 4;
  int c = (int)((e >> 12) & 1023);
  float2 st = stats[c];
  const float cnt = 1.0f / 32768.0f;
  float mean = st.x * cnt;
  float var = st.y * cnt - mean * mean;
  float g = rsqrtf(var + 1e-5f) * gamma[c];
  float sh = beta[c] - mean * g;
  float4 xv = *(const float4*)(x + e);
  uint2 zd = *(const uint2*)(z + e);
  float z0 = bf2f((u16)(zd.x & 0xffff)), z1 = bf2f((u16)(zd.x >> 16));
  float z2 = bf2f((u16)(zd.y & 0xffff)), z3 = bf2f((u16)(zd.y >> 16));
  float4 ov;
  ov.x = xv.x + z0 * g + sh;
  ov.y = xv.y + z1 * g + sh;
  ov.z = xv.z + z2 * g + sh;
  ov.w = xv.w + z3 * g + sh;
  *(float4*)(out + e) = ov;
}

// ---------------------------------------------------------------------------
extern "C" void kernel_launch(void* const* d_in, const int* in_sizes, int n_in,
                              void* d_out, int out_size, void* d_ws,
                              size_t ws_size, hipStream_t stream) {
  const float* x = (const float*)d_in[0];
  const float* theta_w = (const float*)d_in[1];
  const float* theta_b = (const float*)d_in[2];
  const float* phi_w = (const float*)d_in[3];
  const float* phi_b = (const float*)d_in[4];
  const float* g_w = (const float*)d_in[5];
  const float* g_b = (const float*)d_in[6];
  const float* wz_w = (const float*)d_in[7];
  const float* wz_b = (const float*)d_in[8];
  const float* gamma = (const float*)d_in[9];
  const float* beta = (const float*)d_in[10];
  float* out = (float*)d_out;

  char* w = (char*)d_ws;
  const size_t MiB = (size_t)1 << 20;
  u16* WT = (u16*)(w + 0 * MiB);
  u16* WP = (u16*)(w + 1 * MiB);
  u16* WG = (u16*)(w + 2 * MiB);
  u16* WZ = (u16*)(w + 3 * MiB);
  u16* XT = (u16*)(w + 4 * MiB);      // [8][4096][1024] 64 MiB
  u16* XPT = (u16*)(w + 68 * MiB);    // [8][1024][1024] 16 MiB
  u16* THETA = (u16*)(w + 84 * MiB);  // [8][4096][512]  32 MiB
  u16* PHI = (u16*)(w + 116 * MiB);   // [8][1024][512]   8 MiB
  u16* G = (u16*)(w + 124 * MiB);     // [8][512][1024]   8 MiB
  u16* S = XT;                        // reuse xT region (dead after theta GEMM)
  u16* YT = (u16*)(w + 132 * MiB);    // [8][4096][512]  32 MiB
  u16* Z = S;                         // reuse again (P dead after yT GEMM)
  float2* stats = (float2*)(w + 164 * MiB);

  // weights -> bf16 (one launch)
  k_cvt4<<<2048, 256, 0, stream>>>(theta_w, phi_w, g_w, wz_w, WT, WP, WG, WZ);
  // x -> xT, xpT
  k_transpose_pool<<<dim3(16, 32, 8), 256, 0, stream>>>(x, XT, XPT);
  // thetaT[n,ci] = xT @ theta_w^T + theta_b  (batch folded into M=32768)
  gemm256<2><<<dim3(2, 128, 1), 512, 0, stream>>>(
      XT, 0, WT, 0, THETA, 0, theta_b, 512, 1024, 1.0f);
  // phi + g in one launch (512 blocks: fills all CUs)
  gemm_dual<<<512, 256, 0, stream>>>(XPT, WP, WG, PHI, G, phi_b, g_b);
  // S[n,m] = thetaT . phiT^T * scale
  gemm256<0><<<dim3(4, 16, 8), 512, 0, stream>>>(
      THETA, (long)4096 * 512, PHI, (long)1024 * 512, S, (long)4096 * 1024,
      nullptr, 1024, 512, 0.04419417382415922f);
  // softmax rows (in place -> P)
  k_softmax<<<8192, 256, 0, stream>>>(S);
  // yT[n,ci] = P . g^T
  gemm256<0><<<dim3(2, 16, 8), 512, 0, stream>>>(
      S, (long)4096 * 1024, G, (long)512 * 1024, YT, (long)4096 * 512, nullptr,
      512, 1024, 1.0f);
  // z[o,n] = wz . yT^T + wz_b   (bias over row=o)
  gemm256<1><<<dim3(16, 4, 8), 512, 0, stream>>>(
      WZ, 0, YT, (long)4096 * 512, Z, (long)1024 * 4096, wz_b, 4096, 512,
      1.0f);
  // BN stats + apply + residual
  k_stats<<<1024, 256, 0, stream>>>(Z, stats);
  k_apply<<<32768, 256, 0, stream>>>(x, Z, stats, gamma, beta, out);

  (void)in_sizes; (void)n_in; (void)out_size; (void)ws_size;
}